// Round 7
// baseline (204.540 us; speedup 1.0000x reference)
//
#include <hip/hip_runtime.h>

#define HID   1024
#define SLEN  2048
#define NHEAD 16
#define HDIM  64
#define SC2L  0.18033688f   // (1/sqrt(64)) * log2(e)

typedef unsigned short u16;
typedef _Float16 f16;
using bf16x8 = __attribute__((ext_vector_type(8))) short;
using h16x2  = __attribute__((ext_vector_type(2))) __fp16;   // cvt_pkrtz native type
using f16x4  = __attribute__((ext_vector_type(4))) f16;
using f32x4  = __attribute__((ext_vector_type(4))) float;

typedef __attribute__((address_space(1))) void gvoid;
typedef __attribute__((address_space(3))) void lvoid;

__device__ __forceinline__ u16 f2bf(float f) {
  union { float f; unsigned u; } v; v.f = f;
  unsigned u = v.u;
  return (u16)((u + 0x7fffu + ((u >> 16) & 1u)) >> 16);
}

__device__ __forceinline__ void async_ld16(const u16* g, u16* l) {
  __builtin_amdgcn_global_load_lds((gvoid*)g, (lvoid*)l, 16, 0, 0);
}

// -------- prep: z<4 -> transpose+cast weight z; z==4 -> cast X fp32->bf16 --------
__global__ __launch_bounds__(256) void prep_kernel(const float* __restrict__ x,
                                                   const float* __restrict__ wq,
                                                   const float* __restrict__ wk,
                                                   const float* __restrict__ wv,
                                                   const float* __restrict__ wo,
                                                   u16* __restrict__ xb,
                                                   u16* __restrict__ wt) {
  const int tid = threadIdx.x;
  if (blockIdx.z == 4) {
    const int bid = blockIdx.y * 32 + blockIdx.x;
#pragma unroll
    for (int it = 0; it < 4; ++it) {
      const int i = bid * 1024 + it * 256 + tid;
      float4 v = ((const float4*)x)[i];
      ushort4 o;
      o.x = f2bf(v.x); o.y = f2bf(v.y); o.z = f2bf(v.z); o.w = f2bf(v.w);
      ((ushort4*)xb)[i] = o;
    }
    return;
  }
  const float* src = (blockIdx.z == 0) ? wq : (blockIdx.z == 1) ? wk
                   : (blockIdx.z == 2) ? wv : wo;
  u16* dst = wt + (size_t)blockIdx.z * (HID * HID);
  __shared__ float tile[32][33];
  const int n0 = blockIdx.x * 32, k0 = blockIdx.y * 32;
  const int xx = tid & 31, yy = tid >> 5;
  for (int i = yy; i < 32; i += 8)
    tile[i][xx] = src[(size_t)(k0 + i) * HID + n0 + xx];
  __syncthreads();
  for (int i = yy; i < 32; i += 8)
    dst[(size_t)(n0 + i) * HID + k0 + xx] = f2bf(tile[xx][i]);
}

// ------------- fused QKV GEMM (v3: dbuf counted vmcnt + XCD-chunked swizzle) -------------
__global__ __launch_bounds__(256) void gemm_qkv_kernel(const u16* __restrict__ A,
                                                       const u16* __restrict__ Bt,
                                                       const float* __restrict__ bq,
                                                       const float* __restrict__ bk,
                                                       const float* __restrict__ bv,
                                                       u16* __restrict__ Qb,
                                                       u16* __restrict__ Kb,
                                                       u16* __restrict__ VTf) {
  __shared__ u16 smem[16384];                // 2 × (sA 8KB | sB 8KB) = 32 KB
  const int tid  = threadIdx.x;
  const int wave = tid >> 6, lane = tid & 63;
  const int quad = lane >> 4, l16 = lane & 15;
  // XCD-chunked bijective swizzle: 768 blocks = 8 XCDs × 96
  const int raw = blockIdx.y * 24 + blockIdx.x;      // dispatch-linear (x fastest)
  const int logi = (raw & 7) * 96 + (raw >> 3);
  const int bx = logi % 24, by = logi / 24;
  const int n0g = bx * 128;
  const int region = bx >> 3;                // 0=Q 1=K 2=V
  const int colbase = (bx & 7) * 128;
  const int m0 = by * 128;
  const int wm = (wave & 1) * 64, wn = (wave >> 1) * 64;

  f32x4 acc[4][4] = {};
  const int srow = lane >> 2;
  const int scol = (lane & 3) * 8;

#define STAGE_G(kt, bi)                                                          \
  for (int c = wave; c < 8; c += 4) {                                            \
    async_ld16(A  + (size_t)(m0  + c * 16 + srow) * HID + (kt) + scol,           \
               &smem[(bi) * 8192 + c * 512]);                                    \
    async_ld16(Bt + (size_t)(n0g + c * 16 + srow) * HID + (kt) + scol,           \
               &smem[(bi) * 8192 + 4096 + c * 512]);                             \
  }

  STAGE_G(0, 0);
  for (int ks = 0; ks < 32; ++ks) {
    const int bi = ks & 1;
    if (ks < 31) {
      STAGE_G((ks + 1) * 32, bi ^ 1);
      asm volatile("s_waitcnt vmcnt(4)" ::: "memory");  // tile ks ready; ks+1 in flight
    } else {
      asm volatile("s_waitcnt vmcnt(0)" ::: "memory");
    }
    __builtin_amdgcn_s_barrier();              // all waves' tile-ks DMAs landed

    const u16* sA = smem + bi * 8192;
    const u16* sB = smem + bi * 8192 + 4096;
    bf16x8 af[4], bfr[4];
#pragma unroll
    for (int t = 0; t < 4; ++t) {
      af[t]  = *(const bf16x8*)&sA[(wm + t * 16 + l16) * 32 + quad * 8];
      bfr[t] = *(const bf16x8*)&sB[(wn + t * 16 + l16) * 32 + quad * 8];
    }
#pragma unroll
    for (int mt = 0; mt < 4; ++mt)
#pragma unroll
      for (int nt = 0; nt < 4; ++nt)
        acc[mt][nt] = __builtin_amdgcn_mfma_f32_16x16x32_bf16(af[mt], bfr[nt],
                                                              acc[mt][nt], 0, 0, 0);
    __builtin_amdgcn_s_barrier();              // readers done before buf overwrite
  }
#undef STAGE_G

  const float* bias = (region == 0) ? bq : (region == 1) ? bk : bv;
  float bvv[4];
#pragma unroll
  for (int nt = 0; nt < 4; ++nt) bvv[nt] = bias[colbase + wn + nt * 16 + l16];

  if (region == 2) {
    // --- transposed f16 epilogue into the slab/slot layout, two 64-col halves ---
    //   slot(d,half) = (d*2+half) ^ ((d>>2)&1),  half = (s>>3)&1
    const int bb = m0 >> 11;            // batch
    const int m0loc = m0 & 2047;        // s offset within batch
    const int h0 = colbase >> 6;        // first head in this 128-col span
    u16* T = smem;                      // [64 d][128 s] u16, chunk-swizzled
#pragma unroll
    for (int h2 = 0; h2 < 2; ++h2) {
      __syncthreads();                  // prior readers of smem done
      if ((wave >> 1) == h2) {          // waves owning this 64-col half
#pragma unroll
        for (int mt = 0; mt < 4; ++mt)
#pragma unroll
          for (int nt = 0; nt < 4; ++nt)
#pragma unroll
            for (int r = 0; r < 4; ++r) {
              const int sl = (wave & 1) * 64 + mt * 16 + quad * 4 + r;  // 0..127
              const int dl = nt * 16 + l16;                             // 0..63
              union { f16 h; u16 u; } cv;
              cv.h = (f16)(acc[mt][nt][r] + bvv[nt]);
              T[dl * 128 + (((sl >> 3) ^ l16) * 8) + (sl & 7)] = cv.u;
            }
      }
      __syncthreads();
      const int d = tid >> 2, sg = (tid & 3) * 4;
      u16* slab0 = VTf + ((size_t)((bb * NHEAD + h0 + h2) * 128 + (m0loc >> 4))) * 1024;
#pragma unroll
      for (int cc = 0; cc < 4; ++cc) {
        const int cl = sg + cc;
        const int ph = cl ^ (d & 15);
        const int slot = (d * 2 + (cl & 1)) ^ ((d >> 2) & 1);
        *(bf16x8*)(slab0 + (size_t)(cl >> 1) * 1024 + slot * 8)
            = *(const bf16x8*)&T[d * 128 + ph * 8];
      }
    }
    return;
  }

  u16* C = (region == 0) ? Qb : Kb;
#pragma unroll
  for (int mt = 0; mt < 4; ++mt)
#pragma unroll
    for (int r = 0; r < 4; ++r) {
      const int row = m0 + wm + mt * 16 + quad * 4 + r;
#pragma unroll
      for (int nt = 0; nt < 4; ++nt) {
        const int col = colbase + wn + nt * 16 + l16;
        C[(size_t)row * HID + col] = f2bf(acc[mt][nt][r] + bvv[nt]);
      }
    }
}

// ------------- O-proj GEMM (v3: dbuf counted vmcnt + XCD-chunked swizzle) -------------
__global__ __launch_bounds__(256) void gemm_o_kernel(const u16* __restrict__ A,
                                                     const u16* __restrict__ Bt,
                                                     const float* __restrict__ bias,
                                                     float* __restrict__ Cf) {
  __shared__ u16 smem[12288];                // 2 × (sA 4KB | sB 8KB) = 24 KB
  const int tid  = threadIdx.x;
  const int wave = tid >> 6, lane = tid & 63;
  const int quad = lane >> 4, l16 = lane & 15;
  // XCD-chunked bijective swizzle: 512 blocks = 8 XCDs × 64
  const int raw = blockIdx.y * 8 + blockIdx.x;
  const int logi = (raw & 7) * 64 + (raw >> 3);
  const int n0 = (logi & 7) * 128;
  const int m0 = (logi >> 3) * 64;
  const int wn = wave * 32;

  f32x4 acc[4][2] = {};
  const int srow = lane >> 2;
  const int scol = (lane & 3) * 8;

#define STAGE_O(kt, bi)                                                          \
  for (int c = wave; c < 12; c += 4) {                                           \
    if (c < 4) async_ld16(A + (size_t)(m0 + c * 16 + srow) * HID + (kt) + scol,  \
                          &smem[(bi) * 6144 + c * 512]);                         \
    else async_ld16(Bt + (size_t)(n0 + (c - 4) * 16 + srow) * HID + (kt) + scol, \
                    &smem[(bi) * 6144 + 2048 + (c - 4) * 512]);                  \
  }

  STAGE_O(0, 0);
  for (int ks = 0; ks < 32; ++ks) {
    const int bi = ks & 1;
    if (ks < 31) {
      STAGE_O((ks + 1) * 32, bi ^ 1);
      asm volatile("s_waitcnt vmcnt(3)" ::: "memory");  // tile ks ready; ks+1 in flight
    } else {
      asm volatile("s_waitcnt vmcnt(0)" ::: "memory");
    }
    __builtin_amdgcn_s_barrier();

    const u16* sA = smem + bi * 6144;
    const u16* sB = smem + bi * 6144 + 2048;
    bf16x8 af[4], bfr[2];
#pragma unroll
    for (int t = 0; t < 4; ++t)
      af[t] = *(const bf16x8*)&sA[(t * 16 + l16) * 32 + quad * 8];
#pragma unroll
    for (int t = 0; t < 2; ++t)
      bfr[t] = *(const bf16x8*)&sB[(wn + t * 16 + l16) * 32 + quad * 8];
#pragma unroll
    for (int mt = 0; mt < 4; ++mt)
#pragma unroll
      for (int nt = 0; nt < 2; ++nt)
        acc[mt][nt] = __builtin_amdgcn_mfma_f32_16x16x32_bf16(af[mt], bfr[nt],
                                                              acc[mt][nt], 0, 0, 0);
    __builtin_amdgcn_s_barrier();
  }
#undef STAGE_O

  float bvv[2];
#pragma unroll
  for (int nt = 0; nt < 2; ++nt) bvv[nt] = bias[n0 + wn + nt * 16 + l16];
#pragma unroll
  for (int mt = 0; mt < 4; ++mt)
#pragma unroll
    for (int r = 0; r < 4; ++r) {
      const int row = m0 + mt * 16 + quad * 4 + r;
#pragma unroll
      for (int nt = 0; nt < 2; ++nt)
        Cf[(size_t)row * HID + n0 + wn + nt * 16 + l16] = acc[mt][nt][r] + bvv[nt];
    }
}

// ---------------- causal flash attention, v11: paired 1024-block grid ----------------
// 1024 single-q-tile blocks; consecutive pairs are {hot qt=31-qb, cold qt=qb} so
// every 2-block window carries equal work (34 tile-iters) -> CU balance holds for
// ANY dispatch->CU mapping, and 4 blocks/CU (16 waves) instead of 2 (LDS 140KB).
// Barrier-free wave-local j-loop, max 8 outstanding DMA/wave, split K/V waits,
// mask packed to one u32/lane, packed f32->f16 cvt. NO setprio (v10 regression:
// prio-1 MFMA waves starved co-resident waves' DMA issue at low occupancy).
__global__ __launch_bounds__(256, 2) void flash_attn_kernel(const u16* __restrict__ Q,
                                                            const u16* __restrict__ K,
                                                            const u16* __restrict__ VT,
                                                            const int* __restrict__ mask,
                                                            u16* __restrict__ O) {
  const int id = blockIdx.x;
  const int p  = id >> 1, s = id & 1;
  const int hb = p & 31;
  const int h  = hb & 15, b = hb >> 4;
  const int qb = p >> 5;                  // 0..15
  const int qt = s ? qb : 31 - qb;        // hot first within each pair
  const int tid  = threadIdx.x;
  const int wave = tid >> 6, lane = tid & 63;
  const int quad = lane >> 4, l16 = lane & 15;

  __shared__ alignas(16) char smraw[35840];
  u16*   Ks  = (u16*)smraw;                  // [2][4 wv][16 row][64 k] bf16, swizzled chunks
  u16*   Vt  = (u16*)(smraw + 16384);        // [2][4 wv][128 slot][8 f16] wave-local slabs
  float* Ob0 = (float*)smraw;                // [64][66] f32 (epilogue alias)
  float* Ob1 = (float*)(smraw + 16896);
  float* lb  = (float*)(smraw + 33792);      // [4][64]

  const u16* Kh  = K  + (size_t)b * SLEN * HID + h * HDIM;
  const u16* Vth = VT + (size_t)(b * NHEAD + h) * (128 * 1024);

  const int srow8 = lane >> 3;      // row within 8-row chunk
  const int gch   = (lane & 7) ^ srow8;   // xor-swizzled global 16B-chunk index (K)
  const int rx    = l16 & 7;        // K read-side row xor key

  // ---- pack key mask into one u32/lane: lane l covers keys l*32..l*32+31
  unsigned mw = 0;
  {
    const int4* mrow = (const int4*)(mask + b * SLEN);
#pragma unroll
    for (int c = 0; c < 8; ++c) {
      int4 m = mrow[lane * 8 + c];
      mw |= (m.x ? 1u : 0u) << (c * 4);
      mw |= (m.y ? 1u : 0u) << (c * 4 + 1);
      mw |= (m.z ? 1u : 0u) << (c * 4 + 2);
      mw |= (m.w ? 1u : 0u) << (c * 4 + 3);
    }
  }
  const int mb = (wave & 1) * 16 + quad * 4;   // bit base within the shfl'd word

  const int q0 = qt * 64;

  // Q B-frags: B[d=quad*8+j (+32)][q=nt*16+l16]
  bf16x8 qb_[4][2];
#pragma unroll
  for (int nt = 0; nt < 4; ++nt) {
    const u16* qp = Q + (size_t)(b * SLEN + q0 + nt * 16 + l16) * HID + h * HDIM + quad * 8;
    qb_[nt][0] = *(const bf16x8*)qp;
    qb_[nt][1] = *(const bf16x8*)(qp + 32);
  }

  f32x4 oacc[4][4] = {};            // k-partial O^T [dt][nt]
  float l_part[4] = {0.f, 0.f, 0.f, 0.f};

  const int r0s = wave * 16 + srow8;
#define STAGE_KV(jt, bufi)                                                      \
  {                                                                             \
    u16* kd = Ks + (bufi) * 4096 + wave * 1024;                                 \
    async_ld16(Kh + (size_t)((jt) * 64 + r0s) * HID + gch * 8,       kd);       \
    async_ld16(Kh + (size_t)((jt) * 64 + r0s + 8) * HID + gch * 8,   kd + 512); \
    const u16* vs = Vth + (size_t)((jt) * 4 + wave) * 1024;                     \
    u16* vd = Vt + (bufi) * 4096 + wave * 1024;                                 \
    async_ld16(vs + lane * 8,        vd);                                       \
    async_ld16(vs + (64 + lane) * 8, vd + 512);                                 \
  }

  STAGE_KV(0, 0);

  for (int j = 0; j <= qt; ++j) {
    const int buf = j & 1;
    u16* KsB = Ks + buf * 4096;
    u16* VtB = Vt + buf * 4096;

    if (j < qt) {                   // prefetch j+1; max 8 outstanding per wave
      STAGE_KV(j + 1, buf ^ 1);
      asm volatile("s_waitcnt vmcnt(6)" ::: "memory"); // K_j ready; V_j + j+1 fly
    } else {
      asm volatile("s_waitcnt vmcnt(2)" ::: "memory"); // K_j ready; V_j flies
    }

    // per-iteration mask from the packed word (no VMEM)
    const unsigned wbits = __shfl(mw, 2 * j + (wave >> 1));
    float map[4];
#pragma unroll
    for (int r = 0; r < 4; ++r)
      map[r] = ((wbits >> (mb + r)) & 1u) ? 0.f : -1e30f;

    // K A-frags: row = wave*16+l16 (own strip), chunks quad / quad+4
    const u16* kp = KsB + (wave * 16 + l16) * 64;
    const int ph0 = quad ^ rx;
    const bf16x8 ka0 = *(const bf16x8*)(kp + ph0 * 8);
    const bf16x8 ka1 = *(const bf16x8*)(kp + (ph0 ^ 4) * 8);

    float p_[4][4];
#pragma unroll
    for (int nt = 0; nt < 4; ++nt) {
      f32x4 z = {0.f, 0.f, 0.f, 0.f};
      z = __builtin_amdgcn_mfma_f32_16x16x32_bf16(ka0, qb_[nt][0], z, 0, 0, 0);
      z = __builtin_amdgcn_mfma_f32_16x16x32_bf16(ka1, qb_[nt][1], z, 0, 0, 0);
#pragma unroll
      for (int r = 0; r < 4; ++r)
        p_[nt][r] = exp2f(fmaf(z[r], SC2L, map[r]));
    }
    if (j == qt) {   // causal zeroing on diagonal tile (wave-uniform branch)
#pragma unroll
      for (int nt = 0; nt < 4; ++nt)
#pragma unroll
        for (int r = 0; r < 4; ++r)
          if (wave * 16 + quad * 4 + r > nt * 16 + l16) p_[nt][r] = 0.f;
    }

    f16x4 pb[4];
#pragma unroll
    for (int nt = 0; nt < 4; ++nt) {
      l_part[nt] += (p_[nt][0] + p_[nt][1]) + (p_[nt][2] + p_[nt][3]);
      union { h16x2 h[2]; f16x4 v; } u;
      u.h[0] = __builtin_amdgcn_cvt_pkrtz(p_[nt][0], p_[nt][1]);
      u.h[1] = __builtin_amdgcn_cvt_pkrtz(p_[nt][2], p_[nt][3]);
      pb[nt] = u.v;
    }

    if (j < qt) {
      asm volatile("s_waitcnt vmcnt(4)" ::: "memory"); // V_j ready; j+1 flies
    } else {
      asm volatile("s_waitcnt vmcnt(0)" ::: "memory");
    }

    // PV: O^T[d][q] += V^T(own 16-key strip) . P^T
#pragma unroll
    for (int dt = 0; dt < 4; ++dt) {
      const int dd = dt * 16 + l16;
      const int slot = (dd * 2 + (quad >> 1)) ^ ((dd >> 2) & 1);
      const f16x4 va = *(const f16x4*)(VtB + wave * 1024 + slot * 8 + (quad & 1) * 4);
#pragma unroll
      for (int nt = 0; nt < 4; ++nt)
        oacc[dt][nt] = __builtin_amdgcn_mfma_f32_16x16x16f16(va, pb[nt], oacc[dt][nt], 0, 0, 0);
    }
    // no barrier: all LDS traffic in this loop is wave-local
  }
#undef STAGE_KV

  __syncthreads();   // all waves done with Ks/Vt before Ob alias writes

  // ---- epilogue: reduce l over quads; reduce partial O^T across wave pairs ----
#pragma unroll
  for (int nt = 0; nt < 4; ++nt) {
    l_part[nt] += __shfl_xor(l_part[nt], 16);
    l_part[nt] += __shfl_xor(l_part[nt], 32);
  }
  if (quad == 0)
#pragma unroll
    for (int nt = 0; nt < 4; ++nt) lb[wave * 64 + nt * 16 + l16] = l_part[nt];

  if ((wave & 1) == 0) {
    float* ob = (wave == 0) ? Ob0 : Ob1;
#pragma unroll
    for (int dt = 0; dt < 4; ++dt)
#pragma unroll
      for (int nt = 0; nt < 4; ++nt)
#pragma unroll
        for (int r = 0; r < 4; ++r)
          ob[(dt * 16 + quad * 4 + r) * 66 + nt * 16 + l16] = oacc[dt][nt][r];
  }
  __syncthreads();
  if (wave & 1) {
    float* ob = (wave == 1) ? Ob0 : Ob1;
#pragma unroll
    for (int dt = 0; dt < 4; ++dt)
#pragma unroll
      for (int nt = 0; nt < 4; ++nt)
#pragma unroll
        for (int r = 0; r < 4; ++r)
          ob[(dt * 16 + quad * 4 + r) * 66 + nt * 16 + l16] += oacc[dt][nt][r];
  }
  __syncthreads();

  {  // final: thread t -> q = t>>2, 16-d chunk = t&3; normalize + bf16 store
    const int q  = tid >> 2;
    const int dc = tid & 3;
    const float l = lb[q] + lb[64 + q] + lb[128 + q] + lb[192 + q];
    const float inv = 1.f / l;
    u16 ob[16];
#pragma unroll
    for (int e = 0; e < 16; ++e) {
      const int d = dc * 16 + e;
      ob[e] = f2bf((Ob0[d * 66 + q] + Ob1[d * 66 + q]) * inv);
    }
    u16* op = O + (size_t)(b * SLEN + q0 + q) * HID + h * HDIM + dc * 16;
    *(bf16x8*)op       = *(bf16x8*)&ob[0];
    *(bf16x8*)(op + 8) = *(bf16x8*)&ob[8];
  }
}

// ---------------- launcher ----------------
extern "C" void kernel_launch(void* const* d_in, const int* in_sizes, int n_in,
                              void* d_out, int out_size, void* d_ws, size_t ws_size,
                              hipStream_t stream) {
  const float* x    = (const float*)d_in[0];
  const int*   mask = (const int*)d_in[1];
  const float* wq   = (const float*)d_in[2];
  const float* bq   = (const float*)d_in[3];
  const float* wk   = (const float*)d_in[4];
  const float* bk   = (const float*)d_in[5];
  const float* wv   = (const float*)d_in[6];
  const float* bv   = (const float*)d_in[7];
  const float* wo   = (const float*)d_in[8];
  const float* bo   = (const float*)d_in[9];
  float* out = (float*)d_out;

  char* ws = (char*)d_ws;
  u16* XBF = (u16*)(ws);                      // 8 MB (dead after QKV GEMM)
  u16* WT  = (u16*)(ws + (8u  << 20));        // 4x2 MB transposed bf16 weights
  u16* QBF = (u16*)(ws + (16u << 20));        // 8 MB
  u16* KBF = (u16*)(ws + (24u << 20));        // 8 MB
  u16* VTF = (u16*)(ws + (32u << 20));        // 8 MB f16 V^T slab/slot layout
  u16* ATT = (u16*)(ws);                      // 8 MB, reuses XBF slot

  prep_kernel<<<dim3(32, 32, 5), 256, 0, stream>>>(x, wq, wk, wv, wo, XBF, WT);
  gemm_qkv_kernel<<<dim3(24, 32), 256, 0, stream>>>(XBF, WT, bq, bk, bv, QBF, KBF, VTF);
  flash_attn_kernel<<<dim3(1024), 256, 0, stream>>>(QBF, KBF, VTF, mask, ATT);
  gemm_o_kernel<<<dim3(8, 64), 256, 0, stream>>>(ATT, WT + (3u << 20), bo, out);
}

// Round 8
// 195.007 us; speedup vs baseline: 1.0489x; 1.0489x over previous
//
#include <hip/hip_runtime.h>

#define HID   1024
#define SLEN  2048
#define NHEAD 16
#define HDIM  64
#define SC2L  0.18033688f   // (1/sqrt(64)) * log2(e)

typedef unsigned short u16;
typedef _Float16 f16;
using bf16x8 = __attribute__((ext_vector_type(8))) short;
using h16x2  = __attribute__((ext_vector_type(2))) __fp16;   // cvt_pkrtz native type
using f16x4  = __attribute__((ext_vector_type(4))) f16;
using f32x4  = __attribute__((ext_vector_type(4))) float;

typedef __attribute__((address_space(1))) void gvoid;
typedef __attribute__((address_space(3))) void lvoid;

__device__ __forceinline__ u16 f2bf(float f) {
  union { float f; unsigned u; } v; v.f = f;
  unsigned u = v.u;
  return (u16)((u + 0x7fffu + ((u >> 16) & 1u)) >> 16);
}

__device__ __forceinline__ void async_ld16(const u16* g, u16* l) {
  __builtin_amdgcn_global_load_lds((gvoid*)g, (lvoid*)l, 16, 0, 0);
}

// -------- prep: z<4 -> transpose+cast weight z; z==4 -> cast X fp32->bf16 --------
__global__ __launch_bounds__(256) void prep_kernel(const float* __restrict__ x,
                                                   const float* __restrict__ wq,
                                                   const float* __restrict__ wk,
                                                   const float* __restrict__ wv,
                                                   const float* __restrict__ wo,
                                                   u16* __restrict__ xb,
                                                   u16* __restrict__ wt) {
  const int tid = threadIdx.x;
  if (blockIdx.z == 4) {
    const int bid = blockIdx.y * 32 + blockIdx.x;
#pragma unroll
    for (int it = 0; it < 4; ++it) {
      const int i = bid * 1024 + it * 256 + tid;
      float4 v = ((const float4*)x)[i];
      ushort4 o;
      o.x = f2bf(v.x); o.y = f2bf(v.y); o.z = f2bf(v.z); o.w = f2bf(v.w);
      ((ushort4*)xb)[i] = o;
    }
    return;
  }
  const float* src = (blockIdx.z == 0) ? wq : (blockIdx.z == 1) ? wk
                   : (blockIdx.z == 2) ? wv : wo;
  u16* dst = wt + (size_t)blockIdx.z * (HID * HID);
  __shared__ float tile[32][33];
  const int n0 = blockIdx.x * 32, k0 = blockIdx.y * 32;
  const int xx = tid & 31, yy = tid >> 5;
  for (int i = yy; i < 32; i += 8)
    tile[i][xx] = src[(size_t)(k0 + i) * HID + n0 + xx];
  __syncthreads();
  for (int i = yy; i < 32; i += 8)
    dst[(size_t)(n0 + i) * HID + k0 + xx] = f2bf(tile[xx][i]);
}

// ------------- fused QKV GEMM (v3: dbuf counted vmcnt + XCD-chunked swizzle) -------------
__global__ __launch_bounds__(256) void gemm_qkv_kernel(const u16* __restrict__ A,
                                                       const u16* __restrict__ Bt,
                                                       const float* __restrict__ bq,
                                                       const float* __restrict__ bk,
                                                       const float* __restrict__ bv,
                                                       u16* __restrict__ Qb,
                                                       u16* __restrict__ Kb,
                                                       u16* __restrict__ VTf) {
  __shared__ u16 smem[16384];                // 2 × (sA 8KB | sB 8KB) = 32 KB
  const int tid  = threadIdx.x;
  const int wave = tid >> 6, lane = tid & 63;
  const int quad = lane >> 4, l16 = lane & 15;
  // XCD-chunked bijective swizzle: 768 blocks = 8 XCDs × 96
  const int raw = blockIdx.y * 24 + blockIdx.x;      // dispatch-linear (x fastest)
  const int logi = (raw & 7) * 96 + (raw >> 3);
  const int bx = logi % 24, by = logi / 24;
  const int n0g = bx * 128;
  const int region = bx >> 3;                // 0=Q 1=K 2=V
  const int colbase = (bx & 7) * 128;
  const int m0 = by * 128;
  const int wm = (wave & 1) * 64, wn = (wave >> 1) * 64;

  f32x4 acc[4][4] = {};
  const int srow = lane >> 2;
  const int scol = (lane & 3) * 8;

#define STAGE_G(kt, bi)                                                          \
  for (int c = wave; c < 8; c += 4) {                                            \
    async_ld16(A  + (size_t)(m0  + c * 16 + srow) * HID + (kt) + scol,           \
               &smem[(bi) * 8192 + c * 512]);                                    \
    async_ld16(Bt + (size_t)(n0g + c * 16 + srow) * HID + (kt) + scol,           \
               &smem[(bi) * 8192 + 4096 + c * 512]);                             \
  }

  STAGE_G(0, 0);
  for (int ks = 0; ks < 32; ++ks) {
    const int bi = ks & 1;
    if (ks < 31) {
      STAGE_G((ks + 1) * 32, bi ^ 1);
      asm volatile("s_waitcnt vmcnt(4)" ::: "memory");  // tile ks ready; ks+1 in flight
    } else {
      asm volatile("s_waitcnt vmcnt(0)" ::: "memory");
    }
    __builtin_amdgcn_s_barrier();              // all waves' tile-ks DMAs landed

    const u16* sA = smem + bi * 8192;
    const u16* sB = smem + bi * 8192 + 4096;
    bf16x8 af[4], bfr[4];
#pragma unroll
    for (int t = 0; t < 4; ++t) {
      af[t]  = *(const bf16x8*)&sA[(wm + t * 16 + l16) * 32 + quad * 8];
      bfr[t] = *(const bf16x8*)&sB[(wn + t * 16 + l16) * 32 + quad * 8];
    }
#pragma unroll
    for (int mt = 0; mt < 4; ++mt)
#pragma unroll
      for (int nt = 0; nt < 4; ++nt)
        acc[mt][nt] = __builtin_amdgcn_mfma_f32_16x16x32_bf16(af[mt], bfr[nt],
                                                              acc[mt][nt], 0, 0, 0);
    __builtin_amdgcn_s_barrier();              // readers done before buf overwrite
  }
#undef STAGE_G

  const float* bias = (region == 0) ? bq : (region == 1) ? bk : bv;
  float bvv[4];
#pragma unroll
  for (int nt = 0; nt < 4; ++nt) bvv[nt] = bias[colbase + wn + nt * 16 + l16];

  if (region == 2) {
    // --- transposed f16 epilogue into the slab/slot layout, two 64-col halves ---
    //   slot(d,half) = (d*2+half) ^ ((d>>2)&1),  half = (s>>3)&1
    const int bb = m0 >> 11;            // batch
    const int m0loc = m0 & 2047;        // s offset within batch
    const int h0 = colbase >> 6;        // first head in this 128-col span
    u16* T = smem;                      // [64 d][128 s] u16, chunk-swizzled
#pragma unroll
    for (int h2 = 0; h2 < 2; ++h2) {
      __syncthreads();                  // prior readers of smem done
      if ((wave >> 1) == h2) {          // waves owning this 64-col half
#pragma unroll
        for (int mt = 0; mt < 4; ++mt)
#pragma unroll
          for (int nt = 0; nt < 4; ++nt)
#pragma unroll
            for (int r = 0; r < 4; ++r) {
              const int sl = (wave & 1) * 64 + mt * 16 + quad * 4 + r;  // 0..127
              const int dl = nt * 16 + l16;                             // 0..63
              union { f16 h; u16 u; } cv;
              cv.h = (f16)(acc[mt][nt][r] + bvv[nt]);
              T[dl * 128 + (((sl >> 3) ^ l16) * 8) + (sl & 7)] = cv.u;
            }
      }
      __syncthreads();
      const int d = tid >> 2, sg = (tid & 3) * 4;
      u16* slab0 = VTf + ((size_t)((bb * NHEAD + h0 + h2) * 128 + (m0loc >> 4))) * 1024;
#pragma unroll
      for (int cc = 0; cc < 4; ++cc) {
        const int cl = sg + cc;
        const int ph = cl ^ (d & 15);
        const int slot = (d * 2 + (cl & 1)) ^ ((d >> 2) & 1);
        *(bf16x8*)(slab0 + (size_t)(cl >> 1) * 1024 + slot * 8)
            = *(const bf16x8*)&T[d * 128 + ph * 8];
      }
    }
    return;
  }

  u16* C = (region == 0) ? Qb : Kb;
#pragma unroll
  for (int mt = 0; mt < 4; ++mt)
#pragma unroll
    for (int r = 0; r < 4; ++r) {
      const int row = m0 + wm + mt * 16 + quad * 4 + r;
#pragma unroll
      for (int nt = 0; nt < 4; ++nt) {
        const int col = colbase + wn + nt * 16 + l16;
        C[(size_t)row * HID + col] = f2bf(acc[mt][nt][r] + bvv[nt]);
      }
    }
}

// ------------- O-proj GEMM (v3: dbuf counted vmcnt + XCD-chunked swizzle) -------------
__global__ __launch_bounds__(256) void gemm_o_kernel(const u16* __restrict__ A,
                                                     const u16* __restrict__ Bt,
                                                     const float* __restrict__ bias,
                                                     float* __restrict__ Cf) {
  __shared__ u16 smem[12288];                // 2 × (sA 4KB | sB 8KB) = 24 KB
  const int tid  = threadIdx.x;
  const int wave = tid >> 6, lane = tid & 63;
  const int quad = lane >> 4, l16 = lane & 15;
  // XCD-chunked bijective swizzle: 512 blocks = 8 XCDs × 64
  const int raw = blockIdx.y * 8 + blockIdx.x;
  const int logi = (raw & 7) * 64 + (raw >> 3);
  const int n0 = (logi & 7) * 128;
  const int m0 = (logi >> 3) * 64;
  const int wn = wave * 32;

  f32x4 acc[4][2] = {};
  const int srow = lane >> 2;
  const int scol = (lane & 3) * 8;

#define STAGE_O(kt, bi)                                                          \
  for (int c = wave; c < 12; c += 4) {                                           \
    if (c < 4) async_ld16(A + (size_t)(m0 + c * 16 + srow) * HID + (kt) + scol,  \
                          &smem[(bi) * 6144 + c * 512]);                         \
    else async_ld16(Bt + (size_t)(n0 + (c - 4) * 16 + srow) * HID + (kt) + scol, \
                    &smem[(bi) * 6144 + 2048 + (c - 4) * 512]);                  \
  }

  STAGE_O(0, 0);
  for (int ks = 0; ks < 32; ++ks) {
    const int bi = ks & 1;
    if (ks < 31) {
      STAGE_O((ks + 1) * 32, bi ^ 1);
      asm volatile("s_waitcnt vmcnt(3)" ::: "memory");  // tile ks ready; ks+1 in flight
    } else {
      asm volatile("s_waitcnt vmcnt(0)" ::: "memory");
    }
    __builtin_amdgcn_s_barrier();

    const u16* sA = smem + bi * 6144;
    const u16* sB = smem + bi * 6144 + 2048;
    bf16x8 af[4], bfr[2];
#pragma unroll
    for (int t = 0; t < 4; ++t)
      af[t] = *(const bf16x8*)&sA[(t * 16 + l16) * 32 + quad * 8];
#pragma unroll
    for (int t = 0; t < 2; ++t)
      bfr[t] = *(const bf16x8*)&sB[(wn + t * 16 + l16) * 32 + quad * 8];
#pragma unroll
    for (int mt = 0; mt < 4; ++mt)
#pragma unroll
      for (int nt = 0; nt < 2; ++nt)
        acc[mt][nt] = __builtin_amdgcn_mfma_f32_16x16x32_bf16(af[mt], bfr[nt],
                                                              acc[mt][nt], 0, 0, 0);
    __builtin_amdgcn_s_barrier();
  }
#undef STAGE_O

  float bvv[2];
#pragma unroll
  for (int nt = 0; nt < 2; ++nt) bvv[nt] = bias[n0 + wn + nt * 16 + l16];
#pragma unroll
  for (int mt = 0; mt < 4; ++mt)
#pragma unroll
    for (int r = 0; r < 4; ++r) {
      const int row = m0 + mt * 16 + quad * 4 + r;
#pragma unroll
      for (int nt = 0; nt < 2; ++nt)
        Cf[(size_t)row * HID + n0 + wn + nt * 16 + l16] = acc[mt][nt][r] + bvv[nt];
    }
}

// ---------------- causal flash attention, v12: stride-256-class-balanced grid ----------------
// v11 discovery: blocks land on CUs at stride 256, so balance must hold across the
// residue class {c, c+256, c+512, c+768}, not consecutive pairs. Map id = t*256 +
// u*32 + bh (t=id>>8, u=(id>>5)&7, bh=id&31) with qt(t,u) = {u, 15-u, 16+u, 31-u}:
// bijective over qt 0..31, and every residue class sums to exactly 62+4=66 tile
// iterations -> all CUs equal work for any stride-256 round-robin. 4 blocks/CU
// (LDS 140KB, VGPR 84<=128) = 4 waves/SIMD latency hiding. KV stays L3-resident
// (v11: FETCH 20.7MB). Barrier-free wave-local j-loop, split K/V waits, packed
// mask, pkrtz. No setprio. Single change vs v11: the id->qt map.
__global__ __launch_bounds__(256, 2) void flash_attn_kernel(const u16* __restrict__ Q,
                                                            const u16* __restrict__ K,
                                                            const u16* __restrict__ VT,
                                                            const int* __restrict__ mask,
                                                            u16* __restrict__ O) {
  const int id = blockIdx.x;
  const int t_ = id >> 8;                 // 0..3  (stride-256 class selector)
  const int u_ = (id >> 5) & 7;           // 0..7
  const int bh = id & 31;
  const int h  = bh & 15, b = bh >> 4;
  const int qt = (t_ == 0) ? u_ : (t_ == 1) ? (15 - u_)
               : (t_ == 2) ? (16 + u_) : (31 - u_);
  const int tid  = threadIdx.x;
  const int wave = tid >> 6, lane = tid & 63;
  const int quad = lane >> 4, l16 = lane & 15;

  __shared__ alignas(16) char smraw[35840];
  u16*   Ks  = (u16*)smraw;                  // [2][4 wv][16 row][64 k] bf16, swizzled chunks
  u16*   Vt  = (u16*)(smraw + 16384);        // [2][4 wv][128 slot][8 f16] wave-local slabs
  float* Ob0 = (float*)smraw;                // [64][66] f32 (epilogue alias)
  float* Ob1 = (float*)(smraw + 16896);
  float* lb  = (float*)(smraw + 33792);      // [4][64]

  const u16* Kh  = K  + (size_t)b * SLEN * HID + h * HDIM;
  const u16* Vth = VT + (size_t)(b * NHEAD + h) * (128 * 1024);

  const int srow8 = lane >> 3;      // row within 8-row chunk
  const int gch   = (lane & 7) ^ srow8;   // xor-swizzled global 16B-chunk index (K)
  const int rx    = l16 & 7;        // K read-side row xor key

  // ---- pack key mask into one u32/lane: lane l covers keys l*32..l*32+31
  unsigned mw = 0;
  {
    const int4* mrow = (const int4*)(mask + b * SLEN);
#pragma unroll
    for (int c = 0; c < 8; ++c) {
      int4 m = mrow[lane * 8 + c];
      mw |= (m.x ? 1u : 0u) << (c * 4);
      mw |= (m.y ? 1u : 0u) << (c * 4 + 1);
      mw |= (m.z ? 1u : 0u) << (c * 4 + 2);
      mw |= (m.w ? 1u : 0u) << (c * 4 + 3);
    }
  }
  const int mb = (wave & 1) * 16 + quad * 4;   // bit base within the shfl'd word

  const int q0 = qt * 64;

  // Q B-frags: B[d=quad*8+j (+32)][q=nt*16+l16]
  bf16x8 qb_[4][2];
#pragma unroll
  for (int nt = 0; nt < 4; ++nt) {
    const u16* qp = Q + (size_t)(b * SLEN + q0 + nt * 16 + l16) * HID + h * HDIM + quad * 8;
    qb_[nt][0] = *(const bf16x8*)qp;
    qb_[nt][1] = *(const bf16x8*)(qp + 32);
  }

  f32x4 oacc[4][4] = {};            // k-partial O^T [dt][nt]
  float l_part[4] = {0.f, 0.f, 0.f, 0.f};

  const int r0s = wave * 16 + srow8;
#define STAGE_KV(jt, bufi)                                                      \
  {                                                                             \
    u16* kd = Ks + (bufi) * 4096 + wave * 1024;                                 \
    async_ld16(Kh + (size_t)((jt) * 64 + r0s) * HID + gch * 8,       kd);       \
    async_ld16(Kh + (size_t)((jt) * 64 + r0s + 8) * HID + gch * 8,   kd + 512); \
    const u16* vs = Vth + (size_t)((jt) * 4 + wave) * 1024;                     \
    u16* vd = Vt + (bufi) * 4096 + wave * 1024;                                 \
    async_ld16(vs + lane * 8,        vd);                                       \
    async_ld16(vs + (64 + lane) * 8, vd + 512);                                 \
  }

  STAGE_KV(0, 0);

  for (int j = 0; j <= qt; ++j) {
    const int buf = j & 1;
    u16* KsB = Ks + buf * 4096;
    u16* VtB = Vt + buf * 4096;

    if (j < qt) {                   // prefetch j+1; max 8 outstanding per wave
      STAGE_KV(j + 1, buf ^ 1);
      asm volatile("s_waitcnt vmcnt(6)" ::: "memory"); // K_j ready; V_j + j+1 fly
    } else {
      asm volatile("s_waitcnt vmcnt(2)" ::: "memory"); // K_j ready; V_j flies
    }

    // per-iteration mask from the packed word (no VMEM)
    const unsigned wbits = __shfl(mw, 2 * j + (wave >> 1));
    float map[4];
#pragma unroll
    for (int r = 0; r < 4; ++r)
      map[r] = ((wbits >> (mb + r)) & 1u) ? 0.f : -1e30f;

    // K A-frags: row = wave*16+l16 (own strip), chunks quad / quad+4
    const u16* kp = KsB + (wave * 16 + l16) * 64;
    const int ph0 = quad ^ rx;
    const bf16x8 ka0 = *(const bf16x8*)(kp + ph0 * 8);
    const bf16x8 ka1 = *(const bf16x8*)(kp + (ph0 ^ 4) * 8);

    float p_[4][4];
#pragma unroll
    for (int nt = 0; nt < 4; ++nt) {
      f32x4 z = {0.f, 0.f, 0.f, 0.f};
      z = __builtin_amdgcn_mfma_f32_16x16x32_bf16(ka0, qb_[nt][0], z, 0, 0, 0);
      z = __builtin_amdgcn_mfma_f32_16x16x32_bf16(ka1, qb_[nt][1], z, 0, 0, 0);
#pragma unroll
      for (int r = 0; r < 4; ++r)
        p_[nt][r] = exp2f(fmaf(z[r], SC2L, map[r]));
    }
    if (j == qt) {   // causal zeroing on diagonal tile (wave-uniform branch)
#pragma unroll
      for (int nt = 0; nt < 4; ++nt)
#pragma unroll
        for (int r = 0; r < 4; ++r)
          if (wave * 16 + quad * 4 + r > nt * 16 + l16) p_[nt][r] = 0.f;
    }

    f16x4 pb[4];
#pragma unroll
    for (int nt = 0; nt < 4; ++nt) {
      l_part[nt] += (p_[nt][0] + p_[nt][1]) + (p_[nt][2] + p_[nt][3]);
      union { h16x2 h[2]; f16x4 v; } u;
      u.h[0] = __builtin_amdgcn_cvt_pkrtz(p_[nt][0], p_[nt][1]);
      u.h[1] = __builtin_amdgcn_cvt_pkrtz(p_[nt][2], p_[nt][3]);
      pb[nt] = u.v;
    }

    if (j < qt) {
      asm volatile("s_waitcnt vmcnt(4)" ::: "memory"); // V_j ready; j+1 flies
    } else {
      asm volatile("s_waitcnt vmcnt(0)" ::: "memory");
    }

    // PV: O^T[d][q] += V^T(own 16-key strip) . P^T
#pragma unroll
    for (int dt = 0; dt < 4; ++dt) {
      const int dd = dt * 16 + l16;
      const int slot = (dd * 2 + (quad >> 1)) ^ ((dd >> 2) & 1);
      const f16x4 va = *(const f16x4*)(VtB + wave * 1024 + slot * 8 + (quad & 1) * 4);
#pragma unroll
      for (int nt = 0; nt < 4; ++nt)
        oacc[dt][nt] = __builtin_amdgcn_mfma_f32_16x16x16f16(va, pb[nt], oacc[dt][nt], 0, 0, 0);
    }
    // no barrier: all LDS traffic in this loop is wave-local
  }
#undef STAGE_KV

  __syncthreads();   // all waves done with Ks/Vt before Ob alias writes

  // ---- epilogue: reduce l over quads; reduce partial O^T across wave pairs ----
#pragma unroll
  for (int nt = 0; nt < 4; ++nt) {
    l_part[nt] += __shfl_xor(l_part[nt], 16);
    l_part[nt] += __shfl_xor(l_part[nt], 32);
  }
  if (quad == 0)
#pragma unroll
    for (int nt = 0; nt < 4; ++nt) lb[wave * 64 + nt * 16 + l16] = l_part[nt];

  if ((wave & 1) == 0) {
    float* ob = (wave == 0) ? Ob0 : Ob1;
#pragma unroll
    for (int dt = 0; dt < 4; ++dt)
#pragma unroll
      for (int nt = 0; nt < 4; ++nt)
#pragma unroll
        for (int r = 0; r < 4; ++r)
          ob[(dt * 16 + quad * 4 + r) * 66 + nt * 16 + l16] = oacc[dt][nt][r];
  }
  __syncthreads();
  if (wave & 1) {
    float* ob = (wave == 1) ? Ob0 : Ob1;
#pragma unroll
    for (int dt = 0; dt < 4; ++dt)
#pragma unroll
      for (int nt = 0; nt < 4; ++nt)
#pragma unroll
        for (int r = 0; r < 4; ++r)
          ob[(dt * 16 + quad * 4 + r) * 66 + nt * 16 + l16] += oacc[dt][nt][r];
  }
  __syncthreads();

  {  // final: thread t -> q = t>>2, 16-d chunk = t&3; normalize + bf16 store
    const int q  = tid >> 2;
    const int dc = tid & 3;
    const float l = lb[q] + lb[64 + q] + lb[128 + q] + lb[192 + q];
    const float inv = 1.f / l;
    u16 ob[16];
#pragma unroll
    for (int e = 0; e < 16; ++e) {
      const int d = dc * 16 + e;
      ob[e] = f2bf((Ob0[d * 66 + q] + Ob1[d * 66 + q]) * inv);
    }
    u16* op = O + (size_t)(b * SLEN + q0 + q) * HID + h * HDIM + dc * 16;
    *(bf16x8*)op       = *(bf16x8*)&ob[0];
    *(bf16x8*)(op + 8) = *(bf16x8*)&ob[8];
  }
}

// ---------------- launcher ----------------
extern "C" void kernel_launch(void* const* d_in, const int* in_sizes, int n_in,
                              void* d_out, int out_size, void* d_ws, size_t ws_size,
                              hipStream_t stream) {
  const float* x    = (const float*)d_in[0];
  const int*   mask = (const int*)d_in[1];
  const float* wq   = (const float*)d_in[2];
  const float* bq   = (const float*)d_in[3];
  const float* wk   = (const float*)d_in[4];
  const float* bk   = (const float*)d_in[5];
  const float* wv   = (const float*)d_in[6];
  const float* bv   = (const float*)d_in[7];
  const float* wo   = (const float*)d_in[8];
  const float* bo   = (const float*)d_in[9];
  float* out = (float*)d_out;

  char* ws = (char*)d_ws;
  u16* XBF = (u16*)(ws);                      // 8 MB (dead after QKV GEMM)
  u16* WT  = (u16*)(ws + (8u  << 20));        // 4x2 MB transposed bf16 weights
  u16* QBF = (u16*)(ws + (16u << 20));        // 8 MB
  u16* KBF = (u16*)(ws + (24u << 20));        // 8 MB
  u16* VTF = (u16*)(ws + (32u << 20));        // 8 MB f16 V^T slab/slot layout
  u16* ATT = (u16*)(ws);                      // 8 MB, reuses XBF slot

  prep_kernel<<<dim3(32, 32, 5), 256, 0, stream>>>(x, wq, wk, wv, wo, XBF, WT);
  gemm_qkv_kernel<<<dim3(24, 32), 256, 0, stream>>>(XBF, WT, bq, bk, bv, QBF, KBF, VTF);
  flash_attn_kernel<<<dim3(1024), 256, 0, stream>>>(QBF, KBF, VTF, mask, ATT);
  gemm_o_kernel<<<dim3(8, 64), 256, 0, stream>>>(ATT, WT + (3u << 20), bo, out);
}